// Round 3
// baseline (635.989 us; speedup 1.0000x reference)
//
#include <hip/hip_runtime.h>

#define N_NODES 100000
#define IN_F 256
#define OUT_F 128
#define ROWS_PER_SBLK 391                        // ceil(100000/256)

typedef short bf16x8 __attribute__((ext_vector_type(8)));
typedef float f32x4  __attribute__((ext_vector_type(4)));

static __device__ __forceinline__ unsigned short f2bf(float f) {
    unsigned int u = __float_as_uint(f);
    u = (u + 0x7FFF + ((u >> 16) & 1)) >> 16;    // round-to-nearest-even
    return (unsigned short)u;
}

// ---------------- w transpose + bf16 cast ----------------------------------
__global__ __launch_bounds__(256) void wt_kernel(const float* __restrict__ w,
                                                 unsigned short* __restrict__ wT) {
    int n = blockIdx.x;                          // 0..127
    int k = threadIdx.x;                         // 0..255
    wT[n * IN_F + k] = f2bf(w[(size_t)k * OUT_F + n]);
}

// ---------------- MFMA GEMM (B-in-registers) + fused row histogram ----------
// Block 256 threads (4 waves). Wave w owns cols w*32..w*32+31 with the full
// K=256 of W held in VGPR bf16 fragments. One barrier per block.
// Fused: each block histograms 1024 edges of adj_row (3125*1024 == E).
__global__ __launch_bounds__(256) void gemm_mfma_kernel(const float* __restrict__ x,
                                                        const unsigned short* __restrict__ wT,
                                                        unsigned short* __restrict__ supb,
                                                        const int* __restrict__ adj_row,
                                                        int* __restrict__ rowcnt, int E) {
    __shared__ unsigned short A_lds[32][264];    // +8 pad (16.9 KB)

    const int tid  = threadIdx.x;
    const int wave = tid >> 6;                   // 0..3
    const int lane = tid & 63;
    const int quad = lane >> 4;                  // 0..3
    const int l15  = lane & 15;
    const int row_base = blockIdx.x * 32;        // 100000/32 = 3125 exact

    // fused histogram: fire-and-forget atomics, hidden under staging/MFMA
    {
        const int nv4 = E >> 2;
        for (int i = blockIdx.x * 256 + tid; i < nv4; i += 3125 * 256) {
            int4 r4 = ((const int4*)adj_row)[i];
            atomicAdd(&rowcnt[r4.x], 1);
            atomicAdd(&rowcnt[r4.y], 1);
            atomicAdd(&rowcnt[r4.z], 1);
            atomicAdd(&rowcnt[r4.w], 1);
        }
        if (blockIdx.x == 0 && tid < (E & 3))
            atomicAdd(&rowcnt[adj_row[(nv4 << 2) + tid]], 1);
    }

    // B fragments: bfrag[ct][ks] = cols wave*32+ct*16+(0..15), k ks*32+quad*8
    bf16x8 bfrag[2][8];
    {
        const unsigned short* wb = wT + (size_t)(wave * 32 + l15) * IN_F + quad * 8;
#pragma unroll
        for (int ct = 0; ct < 2; ++ct)
#pragma unroll
            for (int ks = 0; ks < 8; ++ks)
                bfrag[ct][ks] = *(const bf16x8*)(wb + ct * 16 * IN_F + ks * 32);
    }

    // stage A: 8192 floats, flat coalesced float4 loads
    {
        const float* xb = x + (size_t)row_base * IN_F;
#pragma unroll
        for (int i = 0; i < 8; ++i) {
            int fidx = i * 1024 + tid * 4;
            float4 a = *(const float4*)(xb + fidx);
            int r = fidx >> 8;
            int c = fidx & 255;
            ushort4 u = {f2bf(a.x), f2bf(a.y), f2bf(a.z), f2bf(a.w)};
            *(ushort4*)&A_lds[r][c] = u;
        }
    }
    __syncthreads();

    f32x4 acc[2][2];
#pragma unroll
    for (int rt = 0; rt < 2; ++rt)
#pragma unroll
        for (int ct = 0; ct < 2; ++ct) acc[rt][ct] = (f32x4){0.f, 0.f, 0.f, 0.f};

#pragma unroll
    for (int ks = 0; ks < 8; ++ks) {
        bf16x8 a0 = *(const bf16x8*)&A_lds[l15][ks * 32 + quad * 8];
        bf16x8 a1 = *(const bf16x8*)&A_lds[16 + l15][ks * 32 + quad * 8];
        acc[0][0] = __builtin_amdgcn_mfma_f32_16x16x32_bf16(a0, bfrag[0][ks], acc[0][0], 0, 0, 0);
        acc[0][1] = __builtin_amdgcn_mfma_f32_16x16x32_bf16(a0, bfrag[1][ks], acc[0][1], 0, 0, 0);
        acc[1][0] = __builtin_amdgcn_mfma_f32_16x16x32_bf16(a1, bfrag[0][ks], acc[1][0], 0, 0, 0);
        acc[1][1] = __builtin_amdgcn_mfma_f32_16x16x32_bf16(a1, bfrag[1][ks], acc[1][1], 0, 0, 0);
    }

    // C/D layout: col = lane&15, row = quad*4 + reg
#pragma unroll
    for (int rt = 0; rt < 2; ++rt)
#pragma unroll
        for (int ct = 0; ct < 2; ++ct)
#pragma unroll
            for (int r = 0; r < 4; ++r) {
                int orow = row_base + rt * 16 + quad * 4 + r;
                int ocol = wave * 32 + ct * 16 + l15;
                supb[(size_t)orow * OUT_F + ocol] = f2bf(acc[rt][ct][r]);
            }
}

// ---------------- scan stage 1: per-block partial sums ----------------------
__global__ __launch_bounds__(256) void scan1_kernel(const int* __restrict__ rowcnt,
                                                    int* __restrict__ bsum) {
    __shared__ int ws[4];
    const int g = blockIdx.x, tid = threadIdx.x;
    const int base = g * ROWS_PER_SBLK;
    int s = 0;
    for (int i = tid; i < ROWS_PER_SBLK; i += 256) {
        int r = base + i;
        if (r < N_NODES) s += rowcnt[r];
    }
#pragma unroll
    for (int d = 1; d < 64; d <<= 1) s += __shfl_xor(s, d, 64);
    if ((tid & 63) == 0) ws[tid >> 6] = s;
    __syncthreads();
    if (tid == 0) bsum[g] = ws[0] + ws[1] + ws[2] + ws[3];
}

// ---------------- scan stage 2: exclusive scan of 256 block sums ------------
__global__ __launch_bounds__(256) void scan2_kernel(const int* __restrict__ bsum,
                                                    int* __restrict__ bbase) {
    __shared__ int ws[4];
    const int tid = threadIdx.x;
    const int lane = tid & 63, wv = tid >> 6;
    int v = bsum[tid];
    int inc = v;
#pragma unroll
    for (int d = 1; d < 64; d <<= 1) {
        int t = __shfl_up(inc, d, 64);
        if (lane >= d) inc += t;
    }
    if (lane == 63) ws[wv] = inc;
    __syncthreads();
    int wb = 0;
    for (int k = 0; k < wv; ++k) wb += ws[k];
    bbase[tid] = wb + inc - v;                   // exclusive prefix
}

// ---------------- scan stage 3: per-block local scan -> rowoff/rowcur -------
__global__ __launch_bounds__(256) void scan3_kernel(const int* __restrict__ rowcnt,
                                                    const int* __restrict__ bbase,
                                                    int* __restrict__ rowoff,
                                                    int* __restrict__ rowcur) {
    __shared__ int ws[4];
    const int g = blockIdx.x, tid = threadIdx.x;
    const int base = g * ROWS_PER_SBLK;
    const int r0 = base + 2 * tid, r1 = r0 + 1;
    const bool ok0 = (2 * tid < ROWS_PER_SBLK) && (r0 < N_NODES);
    const bool ok1 = (2 * tid + 1 < ROWS_PER_SBLK) && (r1 < N_NODES);
    int a = ok0 ? rowcnt[r0] : 0;
    int b = ok1 ? rowcnt[r1] : 0;
    int s = a + b;
    const int lane = tid & 63, wv = tid >> 6;
    int inc = s;
#pragma unroll
    for (int d = 1; d < 64; d <<= 1) {
        int t = __shfl_up(inc, d, 64);
        if (lane >= d) inc += t;
    }
    if (lane == 63) ws[wv] = inc;
    __syncthreads();
    int wb = 0;
    for (int k = 0; k < wv; ++k) wb += ws[k];
    const int excl = bbase[g] + wb + inc - s;
    if (ok0) { rowoff[r0] = excl;     rowcur[r0] = excl; }
    if (ok1) { rowoff[r1] = excl + a; rowcur[r1] = excl + a; }
}

// ---------------- scatter: direct CSR placement -----------------------------
// Row-runs average 32 edges (256 B) so the random 8B stores merge into full
// lines in L2/L3 before writeback.
__global__ __launch_bounds__(256) void scatter_kernel(const int* __restrict__ adj_row,
                                                      const int* __restrict__ adj_col,
                                                      const float* __restrict__ adj_val,
                                                      int* __restrict__ rowcur,
                                                      int2* __restrict__ ebuf, int E) {
    const int gid = blockIdx.x * 256 + threadIdx.x;
    const int nv4 = E >> 2;
    for (int j = gid; j < nv4; j += gridDim.x * 256) {
        int4   r4 = ((const int4*)adj_row)[j];
        int4   c4 = ((const int4*)adj_col)[j];
        float4 v4 = ((const float4*)adj_val)[j];
        int p;
        p = atomicAdd(&rowcur[r4.x], 1); ebuf[p] = make_int2(c4.x, __float_as_int(v4.x));
        p = atomicAdd(&rowcur[r4.y], 1); ebuf[p] = make_int2(c4.y, __float_as_int(v4.y));
        p = atomicAdd(&rowcur[r4.z], 1); ebuf[p] = make_int2(c4.z, __float_as_int(v4.z));
        p = atomicAdd(&rowcur[r4.w], 1); ebuf[p] = make_int2(c4.w, __float_as_int(v4.w));
    }
    if (gid < (E & 3)) {
        int i = (nv4 << 2) + gid;
        int p = atomicAdd(&rowcur[adj_row[i]], 1);
        ebuf[p] = make_int2(adj_col[i], __float_as_int(adj_val[i]));
    }
}

// ---------------- SpMM: CSR streaming gather, LDS-free ----------------------
// Block 256 = 4 waves; wave handles 8 consecutive rows; edge stream per row is
// contiguous and wave-uniform (scalarizable); supb row gathered full-line.
__global__ __launch_bounds__(256) void spmm_kernel(const int2* __restrict__ ebuf,
                                                   const int* __restrict__ rowoff,
                                                   const int* __restrict__ rowend,
                                                   const unsigned short* __restrict__ supb,
                                                   const float* __restrict__ bias,
                                                   float* __restrict__ out) {
    const int tid  = threadIdx.x;
    const int wave = __builtin_amdgcn_readfirstlane(tid >> 6);
    const int lane = tid & 63;
    const int f0   = lane * 2;
    const int rbase = blockIdx.x * 32 + wave * 8;   // 3125*32 = 100000 exact
    const float2 bv = *((const float2*)bias + lane);

    for (int j = 0; j < 8; ++j) {
        const int r = rbase + j;
        const int o = rowoff[r];
        const int c = rowend[r] - o;
        const int2* ep = ebuf + o;
        float2 a = make_float2(0.f, 0.f);
        int i = 0;
        for (; i + 4 <= c; i += 4) {
            int2 e0 = ep[i + 0];
            int2 e1 = ep[i + 1];
            int2 e2 = ep[i + 2];
            int2 e3 = ep[i + 3];
            unsigned int u0 = *(const unsigned int*)(supb + (size_t)e0.x * OUT_F + f0);
            unsigned int u1 = *(const unsigned int*)(supb + (size_t)e1.x * OUT_F + f0);
            unsigned int u2 = *(const unsigned int*)(supb + (size_t)e2.x * OUT_F + f0);
            unsigned int u3 = *(const unsigned int*)(supb + (size_t)e3.x * OUT_F + f0);
            float v0 = __int_as_float(e0.y), v1 = __int_as_float(e1.y);
            float v2 = __int_as_float(e2.y), v3 = __int_as_float(e3.y);
            a.x += v0 * __uint_as_float(u0 << 16);
            a.y += v0 * __uint_as_float(u0 & 0xFFFF0000u);
            a.x += v1 * __uint_as_float(u1 << 16);
            a.y += v1 * __uint_as_float(u1 & 0xFFFF0000u);
            a.x += v2 * __uint_as_float(u2 << 16);
            a.y += v2 * __uint_as_float(u2 & 0xFFFF0000u);
            a.x += v3 * __uint_as_float(u3 << 16);
            a.y += v3 * __uint_as_float(u3 & 0xFFFF0000u);
        }
        for (; i < c; ++i) {
            int2 e = ep[i];
            unsigned int u = *(const unsigned int*)(supb + (size_t)e.x * OUT_F + f0);
            float v = __int_as_float(e.y);
            a.x += v * __uint_as_float(u << 16);
            a.y += v * __uint_as_float(u & 0xFFFF0000u);
        }
        float2 ov;
        ov.x = fmaxf(a.x + bv.x, 0.f);
        ov.y = fmaxf(a.y + bv.y, 0.f);
        *((float2*)(out + (size_t)r * OUT_F) + lane) = ov;
    }
}

extern "C" void kernel_launch(void* const* d_in, const int* in_sizes, int n_in,
                              void* d_out, int out_size, void* d_ws, size_t ws_size,
                              hipStream_t stream) {
    const float* x       = (const float*)d_in[0];
    const int*   adj_row = (const int*)d_in[1];
    const int*   adj_col = (const int*)d_in[2];
    const float* adj_val = (const float*)d_in[3];
    const float* weight  = (const float*)d_in[4];
    const float* bias    = (const float*)d_in[5];
    float* out = (float*)d_out;
    const int E = in_sizes[1];

    char* p = (char*)d_ws;
    unsigned short* supb = (unsigned short*)p;  p += (size_t)N_NODES * OUT_F * 2;  // 25.6 MB
    int2* ebuf           = (int2*)p;            p += (size_t)E * 8;                // 25.6 MB
    unsigned short* wT   = (unsigned short*)p;  p += (size_t)OUT_F * IN_F * 2;     // 64 KB
    int* rowcnt          = (int*)p;             p += (size_t)N_NODES * 4;          // 400 KB
    int* rowoff          = (int*)p;             p += (size_t)N_NODES * 4;          // 400 KB
    int* rowcur          = (int*)p;             p += (size_t)N_NODES * 4;          // 400 KB
    int* bsum            = (int*)p;             p += 256 * 4;
    int* bbase           = (int*)p;             p += 256 * 4;

    hipMemsetAsync(rowcnt, 0, (size_t)N_NODES * 4, stream);
    wt_kernel<<<OUT_F, 256, 0, stream>>>(weight, wT);
    gemm_mfma_kernel<<<N_NODES / 32, 256, 0, stream>>>(x, wT, supb, adj_row, rowcnt, E);
    scan1_kernel<<<256, 256, 0, stream>>>(rowcnt, bsum);
    scan2_kernel<<<1, 256, 0, stream>>>(bsum, bbase);
    scan3_kernel<<<256, 256, 0, stream>>>(rowcnt, bbase, rowoff, rowcur);
    scatter_kernel<<<2048, 256, 0, stream>>>(adj_row, adj_col, adj_val, rowcur, ebuf, E);
    spmm_kernel<<<N_NODES / 32, 256, 0, stream>>>(ebuf, rowoff, rowcur, supb, bias, out);
}